// Round 1
// baseline (450.098 us; speedup 1.0000x reference)
//
#include <hip/hip_runtime.h>
#include <math.h>

#define NTOK 2048
#define DDIM 1024
#define NEXP 8
#define DFF 4096
#define TWODFF 8192
#define BK 64

typedef __attribute__((ext_vector_type(8))) short bf16x8;
typedef __attribute__((ext_vector_type(4))) short bf16x4;
typedef __attribute__((ext_vector_type(4))) float f32x4;

__device__ __forceinline__ short f2bf(float f) {
  unsigned u = __builtin_bit_cast(unsigned, f);
  u = (u + 0x7FFFu + ((u >> 16) & 1u)) >> 16;
  return (short)u;
}

// ---------------- routing: argmax over one-hot dispatch, compact per expert ----
__global__ void route_k(const float* __restrict__ disp, const float* __restrict__ comb,
                        int* __restrict__ cnt, int* __restrict__ tokl,
                        float* __restrict__ scale) {
  __shared__ int lcnt[NEXP];
  const int tid = threadIdx.x;
  if (tid < NEXP) lcnt[tid] = 0;
  __syncthreads();
  for (int i = 0; i < 8; ++i) {
    const int t = i * 256 + tid;
    const float* row = disp + (size_t)t * NEXP;
    int e = 0;
#pragma unroll
    for (int n = 1; n < NEXP; ++n) e = (row[n] > row[e]) ? n : e;
    const float p = comb[(size_t)t * NEXP + e];
    const int slot = atomicAdd(&lcnt[e], 1);
    tokl[e * NTOK + slot] = t;
    scale[t] = p;
  }
  __syncthreads();
  if (tid < NEXP) cnt[tid] = lcnt[tid];
}

// ---------------- GEMM1: act[tok][f] = x * gelu(gate), bf16 out --------------
__global__ __launch_bounds__(256) void gemm1_k(
    const float* __restrict__ hid, const float* __restrict__ Win,
    const float* __restrict__ bin, const int* __restrict__ cnt,
    const int* __restrict__ tokl, short* __restrict__ act) {
  const int e = blockIdx.z;
  const int Me = cnt[e];
  const int m0 = blockIdx.y * 128;
  if (m0 >= Me) return;
  const int f0 = blockIdx.x * 64;

  __shared__ short Al[128 * BK];
  __shared__ short Bl[128 * BK];  // rows 0-63: x-features f0.., rows 64-127: gate
  __shared__ int tokids[128];

  const int tid = threadIdx.x;
  if (tid < 128) {
    const int r = m0 + tid;
    tokids[tid] = (r < Me) ? tokl[e * NTOK + r] : -1;
  }
  __syncthreads();

  const int sr = tid >> 1;
  const int sh = (tid & 1) * 32;
  const int mytok = tokids[sr];
  const float* aSrc = (mytok >= 0) ? (hid + (size_t)mytok * DDIM + sh) : nullptr;
  const int wrow = (sr < 64) ? (f0 + sr) : (DFF + f0 + (sr - 64));
  const float* bSrc = Win + (size_t)e * TWODFF * DDIM + (size_t)wrow * DDIM + sh;

  float4 aReg[8], bReg[8];
  auto load_tile = [&](int k0) {
#pragma unroll
    for (int i = 0; i < 8; ++i) {
      bReg[i] = *(const float4*)(bSrc + k0 + 4 * i);
      aReg[i] = aSrc ? *(const float4*)(aSrc + k0 + 4 * i) : make_float4(0.f, 0.f, 0.f, 0.f);
    }
  };
  auto write_tile = [&]() {
#pragma unroll
    for (int i = 0; i < 8; ++i) {
      const int byteo = (sr * 128 + (sh + 4 * i) * 2) ^ ((sr & 7) << 4);
      bf16x4 av = {f2bf(aReg[i].x), f2bf(aReg[i].y), f2bf(aReg[i].z), f2bf(aReg[i].w)};
      bf16x4 bv = {f2bf(bReg[i].x), f2bf(bReg[i].y), f2bf(bReg[i].z), f2bf(bReg[i].w)};
      *(bf16x4*)((char*)Al + byteo) = av;
      *(bf16x4*)((char*)Bl + byteo) = bv;
    }
  };

  const int wid = tid >> 6, lane = tid & 63;
  const int wm = (wid >> 1) * 64;
  const int wf = (wid & 1) * 32;
  const int lr = lane & 15;
  const int lkb = (lane >> 4) * 16;  // byte offset of this lane's 8-elem k-chunk

  f32x4 accx[4][2], accg[4][2];
  const f32x4 zf = {0.f, 0.f, 0.f, 0.f};
#pragma unroll
  for (int a = 0; a < 4; ++a)
#pragma unroll
    for (int b = 0; b < 2; ++b) { accx[a][b] = zf; accg[a][b] = zf; }

  load_tile(0);
  write_tile();

  for (int kt = 0; kt < 16; ++kt) {
    if (kt < 15) load_tile((kt + 1) * BK);
    __syncthreads();
#pragma unroll
    for (int ks = 0; ks < 2; ++ks) {
      bf16x8 a[4], bx[2], bg[2];
      const int kb = ks * 64 + lkb;
#pragma unroll
      for (int fm = 0; fm < 4; ++fm) {
        const int row = wm + fm * 16 + lr;
        a[fm] = *(const bf16x8*)((const char*)Al + ((row * 128 + kb) ^ ((row & 7) << 4)));
      }
#pragma unroll
      for (int ff = 0; ff < 2; ++ff) {
        const int rx = wf + ff * 16 + lr;
        bx[ff] = *(const bf16x8*)((const char*)Bl + ((rx * 128 + kb) ^ ((rx & 7) << 4)));
        const int rg = rx + 64;
        bg[ff] = *(const bf16x8*)((const char*)Bl + ((rg * 128 + kb) ^ ((rg & 7) << 4)));
      }
#pragma unroll
      for (int fm = 0; fm < 4; ++fm)
#pragma unroll
        for (int ff = 0; ff < 2; ++ff) {
          accx[fm][ff] = __builtin_amdgcn_mfma_f32_16x16x32_bf16(a[fm], bx[ff], accx[fm][ff], 0, 0, 0);
          accg[fm][ff] = __builtin_amdgcn_mfma_f32_16x16x32_bf16(a[fm], bg[ff], accg[fm][ff], 0, 0, 0);
        }
    }
    __syncthreads();
    if (kt < 15) write_tile();
  }

  const int orb = (lane >> 4) * 4;
#pragma unroll
  for (int ff = 0; ff < 2; ++ff) {
    const int fcol = f0 + wf + ff * 16 + lr;
    const float bx_ = bin[e * TWODFF + fcol];
    const float bg_ = bin[e * TWODFF + DFF + fcol];
#pragma unroll
    for (int fm = 0; fm < 4; ++fm)
#pragma unroll
      for (int j = 0; j < 4; ++j) {
        const int row = wm + fm * 16 + orb + j;
        if (m0 + row < Me) {
          const float x = accx[fm][ff][j] + bx_;
          const float g = accg[fm][ff][j] + bg_;
          const float gl = 0.5f * g * (1.f + erff(g * 0.70710678118654752f));
          act[(size_t)tokids[row] * DFF + fcol] = f2bf(x * gl);
        }
      }
  }
}

// ---------------- GEMM2: out[tok][d] = p * (act @ W_out^T + b_out) -----------
__global__ __launch_bounds__(256) void gemm2_k(
    const short* __restrict__ act, const float* __restrict__ Wout,
    const float* __restrict__ bout, const int* __restrict__ cnt,
    const int* __restrict__ tokl, const float* __restrict__ scale,
    float* __restrict__ out) {
  const int e = blockIdx.z;
  const int Me = cnt[e];
  const int m0 = blockIdx.y * 128;
  if (m0 >= Me) return;
  const int n0 = blockIdx.x * 64;

  __shared__ short Al[128 * BK];
  __shared__ short Bl[64 * BK];
  __shared__ int tokids[128];
  __shared__ float pv[128];

  const int tid = threadIdx.x;
  if (tid < 128) {
    const int r = m0 + tid;
    const int tk = (r < Me) ? tokl[e * NTOK + r] : -1;
    tokids[tid] = tk;
    pv[tid] = (tk >= 0) ? scale[tk] : 0.f;
  }
  __syncthreads();

  const int sr = tid >> 1;
  const int sh = (tid & 1) * 32;
  const int mytok = tokids[sr];
  const short* aSrc = (mytok >= 0) ? (act + (size_t)mytok * DFF + sh) : nullptr;
  const int rb = tid >> 2, q = tid & 3;
  const float* bSrc = Wout + (size_t)e * DDIM * DFF + (size_t)(n0 + rb) * DFF + q * 16;

  bf16x8 aReg[4];
  float4 bReg[4];
  auto load_tile = [&](int k0) {
#pragma unroll
    for (int i = 0; i < 4; ++i) bReg[i] = *(const float4*)(bSrc + k0 + 4 * i);
    if (aSrc) {
#pragma unroll
      for (int i = 0; i < 4; ++i) aReg[i] = *(const bf16x8*)(aSrc + k0 + 8 * i);
    } else {
      const bf16x8 z = {0, 0, 0, 0, 0, 0, 0, 0};
#pragma unroll
      for (int i = 0; i < 4; ++i) aReg[i] = z;
    }
  };
  auto write_tile = [&]() {
#pragma unroll
    for (int i = 0; i < 4; ++i) {
      const int ba = (sr * 128 + (sh + 8 * i) * 2) ^ ((sr & 7) << 4);
      *(bf16x8*)((char*)Al + ba) = aReg[i];
    }
#pragma unroll
    for (int i = 0; i < 4; ++i) {
      const int bb = (rb * 128 + (q * 16 + 4 * i) * 2) ^ ((rb & 7) << 4);
      bf16x4 bv = {f2bf(bReg[i].x), f2bf(bReg[i].y), f2bf(bReg[i].z), f2bf(bReg[i].w)};
      *(bf16x4*)((char*)Bl + bb) = bv;
    }
  };

  const int wid = tid >> 6, lane = tid & 63;
  const int wm = (wid >> 1) * 64;
  const int wn = (wid & 1) * 32;
  const int lr = lane & 15;
  const int lkb = (lane >> 4) * 16;

  f32x4 acc[4][2];
  const f32x4 zf = {0.f, 0.f, 0.f, 0.f};
#pragma unroll
  for (int a = 0; a < 4; ++a) { acc[a][0] = zf; acc[a][1] = zf; }

  load_tile(0);
  write_tile();

  for (int kt = 0; kt < 64; ++kt) {
    if (kt < 63) load_tile((kt + 1) * BK);
    __syncthreads();
#pragma unroll
    for (int ks = 0; ks < 2; ++ks) {
      bf16x8 a[4], b[2];
      const int kb = ks * 64 + lkb;
#pragma unroll
      for (int fm = 0; fm < 4; ++fm) {
        const int row = wm + fm * 16 + lr;
        a[fm] = *(const bf16x8*)((const char*)Al + ((row * 128 + kb) ^ ((row & 7) << 4)));
      }
#pragma unroll
      for (int ff = 0; ff < 2; ++ff) {
        const int rn = wn + ff * 16 + lr;
        b[ff] = *(const bf16x8*)((const char*)Bl + ((rn * 128 + kb) ^ ((rn & 7) << 4)));
      }
#pragma unroll
      for (int fm = 0; fm < 4; ++fm)
#pragma unroll
        for (int ff = 0; ff < 2; ++ff)
          acc[fm][ff] = __builtin_amdgcn_mfma_f32_16x16x32_bf16(a[fm], b[ff], acc[fm][ff], 0, 0, 0);
    }
    __syncthreads();
    if (kt < 63) write_tile();
  }

  const int orb = (lane >> 4) * 4;
#pragma unroll
  for (int ff = 0; ff < 2; ++ff) {
    const int ncol = n0 + wn + ff * 16 + lr;
    const float bo = bout[e * DDIM + ncol];
#pragma unroll
    for (int fm = 0; fm < 4; ++fm)
#pragma unroll
      for (int j = 0; j < 4; ++j) {
        const int row = wm + fm * 16 + orb + j;
        if (m0 + row < Me)
          out[(size_t)tokids[row] * DDIM + ncol] = pv[row] * (acc[fm][ff][j] + bo);
      }
  }
}

extern "C" void kernel_launch(void* const* d_in, const int* in_sizes, int n_in,
                              void* d_out, int out_size, void* d_ws, size_t ws_size,
                              hipStream_t stream) {
  const float* hid = (const float*)d_in[0];
  const float* disp = (const float*)d_in[1];
  const float* comb = (const float*)d_in[2];
  const float* Win = (const float*)d_in[3];
  const float* bin = (const float*)d_in[4];
  const float* Wout = (const float*)d_in[5];
  const float* bout = (const float*)d_in[6];
  float* out = (float*)d_out;

  char* ws = (char*)d_ws;
  int* cnt = (int*)(ws);
  int* tokl = (int*)(ws + 256);
  float* scale = (float*)(ws + 256 + NTOK * NEXP * 4);
  short* act = (short*)(ws + (1 << 17));

  route_k<<<1, 256, 0, stream>>>(disp, comb, cnt, tokl, scale);
  gemm1_k<<<dim3(DFF / 64, 4, NEXP), 256, 0, stream>>>(hid, Win, bin, cnt, tokl, act);
  gemm2_k<<<dim3(DDIM / 64, 4, NEXP), 256, 0, stream>>>(act, Wout, bout, cnt, tokl, scale, out);
}

// Round 2
// 203.793 us; speedup vs baseline: 2.2086x; 2.2086x over previous
//
#include <hip/hip_runtime.h>
#include <math.h>

#define NTOK 2048
#define DDIM 1024
#define NEXP 8
#define DFF 4096
#define TWODFF 8192

typedef __attribute__((ext_vector_type(8))) short bf16x8;
typedef __attribute__((ext_vector_type(4))) short bf16x4;
typedef __attribute__((ext_vector_type(4))) float f32x4;

__device__ __forceinline__ short f2bf(float f) {
  unsigned u = __builtin_bit_cast(unsigned, f);
  u = (u + 0x7FFFu + ((u >> 16) & 1u)) >> 16;
  return (short)u;
}

// packed f32 pair -> 2x bf16 (D.lo = S0, D.hi = S1), RTNE
__device__ __forceinline__ unsigned pk2(float a, float b) {
  unsigned r;
  asm("v_cvt_pk_bf16_f32 %0, %1, %2" : "=v"(r) : "v"(a), "v"(b));
  return r;
}

// ---------------- routing ----------------
__global__ void route_k(const float* __restrict__ disp, const float* __restrict__ comb,
                        int* __restrict__ cnt, int* __restrict__ tokl,
                        float* __restrict__ scale) {
  __shared__ int lcnt[NEXP];
  const int tid = threadIdx.x;
  if (tid < NEXP) lcnt[tid] = 0;
  __syncthreads();
  for (int i = 0; i < 8; ++i) {
    const int t = i * 256 + tid;
    const float* row = disp + (size_t)t * NEXP;
    int e = 0;
#pragma unroll
    for (int n = 1; n < NEXP; ++n) e = (row[n] > row[e]) ? n : e;
    const float p = comb[(size_t)t * NEXP + e];
    const int slot = atomicAdd(&lcnt[e], 1);
    tokl[e * NTOK + slot] = t;
    scale[t] = p;
  }
  __syncthreads();
  if (tid < NEXP) cnt[tid] = lcnt[tid];
}

// ---------------- GEMM1: act = x * gelu(gate), bf16 out ----------------
// tile: 128 tokens x 64 f-cols (x + gate), BK=32, dbuf LDS, 1 barrier/step
__global__ __launch_bounds__(256) void gemm1_k(
    const float* __restrict__ hid, const float* __restrict__ Win,
    const float* __restrict__ bin, const int* __restrict__ cnt,
    const int* __restrict__ tokl, short* __restrict__ act) {
  const int e = blockIdx.z;
  const int Me = cnt[e];
  const int m0 = blockIdx.y * 128;
  if (m0 >= Me) return;
  const int f0 = blockIdx.x * 64;

  __shared__ short Al[2][128 * 32];  // row stride 32 bf16 = 64 B
  __shared__ short Bl[2][128 * 32];  // rows 0-63 x, 64-127 gate
  __shared__ int tokids[128];

  const int tid = threadIdx.x;
  if (tid < 128) {
    const int r = m0 + tid;
    tokids[tid] = (r < Me) ? tokl[e * NTOK + r] : -1;
  }
  __syncthreads();

  // staging: li = i*256 + tid -> row = i*32 + (tid>>3), col = (tid&7)*4 floats
  const int r0 = tid >> 3;
  const int c0 = (tid & 7) * 4;
  const float* aP[4];
  const float* bP[4];
#pragma unroll
  for (int i = 0; i < 4; ++i) {
    const int row = i * 32 + r0;
    const int tk = tokids[row];
    aP[i] = (tk >= 0) ? (hid + (size_t)tk * DDIM + c0) : nullptr;
    const int wr = (row < 64) ? (f0 + row) : (DFF + f0 + (row - 64));
    bP[i] = Win + (size_t)e * TWODFF * DDIM + (size_t)wr * DDIM + c0;
  }

  float4 aR[4], bR[4];
  auto load_t = [&](int k0) {
#pragma unroll
    for (int i = 0; i < 4; ++i) {
      bR[i] = *(const float4*)(bP[i] + k0);
      aR[i] = aP[i] ? *(const float4*)(aP[i] + k0) : make_float4(0.f, 0.f, 0.f, 0.f);
    }
  };
  auto store_t = [&](int buf) {
#pragma unroll
    for (int i = 0; i < 4; ++i) {
      const int row = i * 32 + r0;
      const int ba = (row * 64 + (tid & 7) * 8) ^ ((row & 7) << 4);
      uint2 va, vb;
      va.x = pk2(aR[i].x, aR[i].y); va.y = pk2(aR[i].z, aR[i].w);
      vb.x = pk2(bR[i].x, bR[i].y); vb.y = pk2(bR[i].z, bR[i].w);
      *(uint2*)((char*)Al[buf] + ba) = va;
      *(uint2*)((char*)Bl[buf] + ba) = vb;
    }
  };

  const int wid = tid >> 6, lane = tid & 63;
  const int wm = (wid >> 1) * 64;
  const int wf = (wid & 1) * 32;
  const int lr = lane & 15;
  const int kbyte = (lane >> 4) * 16;

  f32x4 accx[4][2], accg[4][2];
  const f32x4 zf = {0.f, 0.f, 0.f, 0.f};
#pragma unroll
  for (int a = 0; a < 4; ++a)
#pragma unroll
    for (int b = 0; b < 2; ++b) { accx[a][b] = zf; accg[a][b] = zf; }

  load_t(0);
  store_t(0);

  for (int kt = 0; kt < 32; ++kt) {
    if (kt < 31) load_t((kt + 1) * 32);
    __syncthreads();
    const char* Ab = (const char*)Al[kt & 1];
    const char* Bb = (const char*)Bl[kt & 1];
    bf16x8 a[4], bx[2], bg[2];
#pragma unroll
    for (int fm = 0; fm < 4; ++fm) {
      const int row = wm + fm * 16 + lr;
      a[fm] = *(const bf16x8*)(Ab + ((row * 64 + kbyte) ^ ((row & 7) << 4)));
    }
#pragma unroll
    for (int ff = 0; ff < 2; ++ff) {
      const int rx = wf + ff * 16 + lr;
      bx[ff] = *(const bf16x8*)(Bb + ((rx * 64 + kbyte) ^ ((rx & 7) << 4)));
      const int rg = rx + 64;
      bg[ff] = *(const bf16x8*)(Bb + ((rg * 64 + kbyte) ^ ((rg & 7) << 4)));
    }
#pragma unroll
    for (int fm = 0; fm < 4; ++fm)
#pragma unroll
      for (int ff = 0; ff < 2; ++ff) {
        accx[fm][ff] = __builtin_amdgcn_mfma_f32_16x16x32_bf16(a[fm], bx[ff], accx[fm][ff], 0, 0, 0);
        accg[fm][ff] = __builtin_amdgcn_mfma_f32_16x16x32_bf16(a[fm], bg[ff], accg[fm][ff], 0, 0, 0);
      }
    if (kt < 31) store_t((kt + 1) & 1);
  }

  const int orb = (lane >> 4) * 4;
#pragma unroll
  for (int ff = 0; ff < 2; ++ff) {
    const int fcol = f0 + wf + ff * 16 + lr;
    const float bx_ = bin[e * TWODFF + fcol];
    const float bg_ = bin[e * TWODFF + DFF + fcol];
#pragma unroll
    for (int fm = 0; fm < 4; ++fm)
#pragma unroll
      for (int j = 0; j < 4; ++j) {
        const int row = wm + fm * 16 + orb + j;
        if (m0 + row < Me) {
          const float x = accx[fm][ff][j] + bx_;
          const float g = accg[fm][ff][j] + bg_;
          const float gl = 0.5f * g * (1.f + erff(g * 0.70710678118654752f));
          act[(size_t)tokids[row] * DFF + fcol] = f2bf(x * gl);
        }
      }
  }
}

// ---------------- GEMM2: out = p * (act @ W_out^T + b_out) ----------------
// tile: 128 tokens x 64 d-cols, BK=64, dbuf LDS, 1 barrier/step
__global__ __launch_bounds__(256) void gemm2_k(
    const short* __restrict__ act, const float* __restrict__ Wout,
    const float* __restrict__ bout, const int* __restrict__ cnt,
    const int* __restrict__ tokl, const float* __restrict__ scale,
    float* __restrict__ out) {
  const int e = blockIdx.z;
  const int Me = cnt[e];
  const int m0 = blockIdx.y * 128;
  if (m0 >= Me) return;
  const int n0 = blockIdx.x * 64;

  __shared__ short Al[2][128 * 64];  // row stride 64 bf16 = 128 B
  __shared__ short Bl[2][64 * 64];
  __shared__ int tokids[128];
  __shared__ float pv[128];

  const int tid = threadIdx.x;
  if (tid < 128) {
    const int r = m0 + tid;
    const int tk = (r < Me) ? tokl[e * NTOK + r] : -1;
    tokids[tid] = tk;
    pv[tid] = (tk >= 0) ? scale[tk] : 0.f;
  }
  __syncthreads();

  // A staging: li = i*256+tid -> row = i*32 + (tid>>3), col = (tid&7)*8 bf16
  const int ar0 = tid >> 3;
  const int ac0 = (tid & 7) * 8;
  const short* aP[4];
#pragma unroll
  for (int i = 0; i < 4; ++i) {
    const int row = i * 32 + ar0;
    const int tk = tokids[row];
    aP[i] = (tk >= 0) ? (act + (size_t)tk * DFF + ac0) : nullptr;
  }
  // B staging: li = i*256+tid -> row = i*16 + (tid>>4), col = (tid&15)*4 floats
  const int br0 = tid >> 4;
  const int bc0 = (tid & 15) * 4;
  const float* bP[4];
#pragma unroll
  for (int i = 0; i < 4; ++i) {
    const int row = i * 16 + br0;
    bP[i] = Wout + (size_t)e * DDIM * DFF + (size_t)(n0 + row) * DFF + bc0;
  }

  bf16x8 aR[4];
  float4 bR[4];
  auto load_t = [&](int k0) {
#pragma unroll
    for (int i = 0; i < 4; ++i) bR[i] = *(const float4*)(bP[i] + k0);
    const bf16x8 z = {0, 0, 0, 0, 0, 0, 0, 0};
#pragma unroll
    for (int i = 0; i < 4; ++i) aR[i] = aP[i] ? *(const bf16x8*)(aP[i] + k0) : z;
  };
  auto store_t = [&](int buf) {
#pragma unroll
    for (int i = 0; i < 4; ++i) {
      const int row = i * 32 + ar0;
      const int ba = (row * 128 + (tid & 7) * 16) ^ ((row & 7) << 4);
      *(bf16x8*)((char*)Al[buf] + ba) = aR[i];
    }
#pragma unroll
    for (int i = 0; i < 4; ++i) {
      const int row = i * 16 + br0;
      const int bb = (row * 128 + (tid & 15) * 8) ^ ((row & 7) << 4);
      uint2 vb;
      vb.x = pk2(bR[i].x, bR[i].y); vb.y = pk2(bR[i].z, bR[i].w);
      *(uint2*)((char*)Bl[buf] + bb) = vb;
    }
  };

  const int wid = tid >> 6, lane = tid & 63;
  const int wm = (wid >> 1) * 64;
  const int wn = (wid & 1) * 32;
  const int lr = lane & 15;
  const int lkb = (lane >> 4) * 16;

  f32x4 acc[4][2];
  const f32x4 zf = {0.f, 0.f, 0.f, 0.f};
#pragma unroll
  for (int a = 0; a < 4; ++a) { acc[a][0] = zf; acc[a][1] = zf; }

  load_t(0);
  store_t(0);

  for (int kt = 0; kt < 64; ++kt) {
    if (kt < 63) load_t((kt + 1) * 64);
    __syncthreads();
    const char* Ab = (const char*)Al[kt & 1];
    const char* Bb = (const char*)Bl[kt & 1];
#pragma unroll
    for (int ks = 0; ks < 2; ++ks) {
      bf16x8 a[4], b[2];
      const int kb = ks * 64 + lkb;
#pragma unroll
      for (int fm = 0; fm < 4; ++fm) {
        const int row = wm + fm * 16 + lr;
        a[fm] = *(const bf16x8*)(Ab + ((row * 128 + kb) ^ ((row & 7) << 4)));
      }
#pragma unroll
      for (int ff = 0; ff < 2; ++ff) {
        const int rn = wn + ff * 16 + lr;
        b[ff] = *(const bf16x8*)(Bb + ((rn * 128 + kb) ^ ((rn & 7) << 4)));
      }
#pragma unroll
      for (int fm = 0; fm < 4; ++fm)
#pragma unroll
        for (int ff = 0; ff < 2; ++ff)
          acc[fm][ff] = __builtin_amdgcn_mfma_f32_16x16x32_bf16(a[fm], b[ff], acc[fm][ff], 0, 0, 0);
    }
    if (kt < 63) store_t((kt + 1) & 1);
  }

  const int orb = (lane >> 4) * 4;
#pragma unroll
  for (int ff = 0; ff < 2; ++ff) {
    const int ncol = n0 + wn + ff * 16 + lr;
    const float bo = bout[e * DDIM + ncol];
#pragma unroll
    for (int fm = 0; fm < 4; ++fm)
#pragma unroll
      for (int j = 0; j < 4; ++j) {
        const int row = wm + fm * 16 + orb + j;
        if (m0 + row < Me)
          out[(size_t)tokids[row] * DDIM + ncol] = pv[row] * (acc[fm][ff][j] + bo);
      }
  }
}

extern "C" void kernel_launch(void* const* d_in, const int* in_sizes, int n_in,
                              void* d_out, int out_size, void* d_ws, size_t ws_size,
                              hipStream_t stream) {
  const float* hid = (const float*)d_in[0];
  const float* disp = (const float*)d_in[1];
  const float* comb = (const float*)d_in[2];
  const float* Win = (const float*)d_in[3];
  const float* bin = (const float*)d_in[4];
  const float* Wout = (const float*)d_in[5];
  const float* bout = (const float*)d_in[6];
  float* out = (float*)d_out;

  char* ws = (char*)d_ws;
  int* cnt = (int*)(ws);
  int* tokl = (int*)(ws + 256);
  float* scale = (float*)(ws + 256 + NTOK * NEXP * 4);
  short* act = (short*)(ws + (1 << 17));

  route_k<<<1, 256, 0, stream>>>(disp, comb, cnt, tokl, scale);
  gemm1_k<<<dim3(DFF / 64, 4, NEXP), 256, 0, stream>>>(hid, Win, bin, cnt, tokl, act);
  gemm2_k<<<dim3(DDIM / 64, 4, NEXP), 256, 0, stream>>>(act, Wout, bout, cnt, tokl, scale, out);
}

// Round 4
// 201.937 us; speedup vs baseline: 2.2289x; 1.0092x over previous
//
#include <hip/hip_runtime.h>
#include <math.h>

#define NTOK 2048
#define DDIM 1024
#define NEXP 8
#define DFF 4096
#define TWODFF 8192

typedef __attribute__((ext_vector_type(8))) short bf16x8;
typedef __attribute__((ext_vector_type(4))) float f32x4;

__device__ __forceinline__ short f2bf(float f) {
  unsigned u = __builtin_bit_cast(unsigned, f);
  u = (u + 0x7FFFu + ((u >> 16) & 1u)) >> 16;
  return (short)u;
}

// packed f32 pair -> 2x bf16 (D.lo = a, D.hi = b), RTNE
__device__ __forceinline__ unsigned pk2(float a, float b) {
  unsigned r;
  asm("v_cvt_pk_bf16_f32 %0, %1, %2" : "=v"(r) : "v"(a), "v"(b));
  return r;
}

// ---------------- routing ----------------
__global__ void route_k(const float* __restrict__ disp, const float* __restrict__ comb,
                        int* __restrict__ cnt, int* __restrict__ tokl,
                        float* __restrict__ scale) {
  __shared__ int lcnt[NEXP];
  const int tid = threadIdx.x;
  if (tid < NEXP) lcnt[tid] = 0;
  __syncthreads();
  for (int i = 0; i < 8; ++i) {
    const int t = i * 256 + tid;
    const float* row = disp + (size_t)t * NEXP;
    int e = 0;
#pragma unroll
    for (int n = 1; n < NEXP; ++n) e = (row[n] > row[e]) ? n : e;
    const float p = comb[(size_t)t * NEXP + e];
    const int slot = atomicAdd(&lcnt[e], 1);
    tokl[e * NTOK + slot] = t;
    scale[t] = p;
  }
  __syncthreads();
  if (tid < NEXP) cnt[tid] = lcnt[tid];
}

// ---------------- GEMM1: act = x * gelu(gate), bf16 out ----------------
// BM=256 tok, 128 f-cols (B-tile 256 wrows: x then gate), BK=32, 8 waves 2m x 4f
__global__ __launch_bounds__(512) void gemm1_k(
    const float* __restrict__ hid, const float* __restrict__ Win,
    const float* __restrict__ bin, const int* __restrict__ cnt,
    const int* __restrict__ tokl, short* __restrict__ act) {
  // XCD-pinned remap: flat id % 8 == expert
  const int bid = blockIdx.x + 32 * (blockIdx.y + 2 * blockIdx.z);
  const int e = bid & 7;
  const int rem = bid >> 3;
  const int f0 = (rem & 31) * 128;
  const int m0 = (rem >> 5) * 256;
  const int Me = cnt[e];
  if (m0 >= Me) return;

  __shared__ short Al[2][256 * 32];  // row stride 32 bf16 = 64 B
  __shared__ short Bl[2][256 * 32];  // rows 0-127: x(f0..f0+128), 128-255: gate
  __shared__ int tokids[256];

  const int tid = threadIdx.x;
  if (tid < 256) {
    const int r = m0 + tid;
    tokids[tid] = (r < Me) ? tokl[e * NTOK + r] : -1;
  }
  __syncthreads();

  // staging: load i -> row = i*64 + (tid>>3), col = (tid&7)*4 floats
  const int r0 = tid >> 3;
  const int c0 = (tid & 7) * 4;
  const float* aP[4];
  const float* bP[4];
#pragma unroll
  for (int i = 0; i < 4; ++i) {
    const int row = i * 64 + r0;
    const int tk = tokids[row];
    aP[i] = (tk >= 0) ? (hid + (size_t)tk * DDIM + c0) : nullptr;
    const int wr = (row < 128) ? (f0 + row) : (DFF + f0 + (row - 128));
    bP[i] = Win + (size_t)e * TWODFF * DDIM + (size_t)wr * DDIM + c0;
  }

  float4 aR[4], bR[4];
  auto load_t = [&](int k0) {
#pragma unroll
    for (int i = 0; i < 4; ++i) {
      bR[i] = *(const float4*)(bP[i] + k0);
      aR[i] = aP[i] ? *(const float4*)(aP[i] + k0) : make_float4(0.f, 0.f, 0.f, 0.f);
    }
  };
  auto store_t = [&](int buf) {
#pragma unroll
    for (int i = 0; i < 4; ++i) {
      const int row = i * 64 + r0;
      const int ba = (row * 64 + (tid & 7) * 8) ^ ((row & 7) << 4);
      uint2 va, vb;
      va.x = pk2(aR[i].x, aR[i].y); va.y = pk2(aR[i].z, aR[i].w);
      vb.x = pk2(bR[i].x, bR[i].y); vb.y = pk2(bR[i].z, bR[i].w);
      *(uint2*)((char*)Al[buf] + ba) = va;
      *(uint2*)((char*)Bl[buf] + ba) = vb;
    }
  };

  const int wid = tid >> 6, lane = tid & 63;
  const int mi = wid >> 2;            // 0..1 -> m-half 128 rows
  const int fi = wid & 3;             // 0..3 -> 32 f-cols
  const int lr = lane & 15;
  const int kbyte = (lane >> 4) * 16;

  f32x4 accx[8][2], accg[8][2];
  const f32x4 zf = {0.f, 0.f, 0.f, 0.f};
#pragma unroll
  for (int a = 0; a < 8; ++a)
#pragma unroll
    for (int b = 0; b < 2; ++b) { accx[a][b] = zf; accg[a][b] = zf; }

  load_t(0);
  store_t(0);

  for (int kt = 0; kt < 32; ++kt) {
    if (kt < 31) load_t((kt + 1) * 32);
    __syncthreads();
    const char* Ab = (const char*)Al[kt & 1];
    const char* Bb = (const char*)Bl[kt & 1];
    bf16x8 a[8], bx[2], bg[2];
#pragma unroll
    for (int fm = 0; fm < 8; ++fm) {
      const int row = mi * 128 + fm * 16 + lr;
      a[fm] = *(const bf16x8*)(Ab + ((row * 64 + kbyte) ^ ((row & 7) << 4)));
    }
#pragma unroll
    for (int ff = 0; ff < 2; ++ff) {
      const int rx = fi * 32 + ff * 16 + lr;
      bx[ff] = *(const bf16x8*)(Bb + ((rx * 64 + kbyte) ^ ((rx & 7) << 4)));
      const int rg = rx + 128;
      bg[ff] = *(const bf16x8*)(Bb + ((rg * 64 + kbyte) ^ ((rg & 7) << 4)));
    }
#pragma unroll
    for (int fm = 0; fm < 8; ++fm)
#pragma unroll
      for (int ff = 0; ff < 2; ++ff) {
        accx[fm][ff] = __builtin_amdgcn_mfma_f32_16x16x32_bf16(a[fm], bx[ff], accx[fm][ff], 0, 0, 0);
        accg[fm][ff] = __builtin_amdgcn_mfma_f32_16x16x32_bf16(a[fm], bg[ff], accg[fm][ff], 0, 0, 0);
      }
    if (kt < 31) store_t((kt + 1) & 1);
  }

  const int orb = (lane >> 4) * 4;
#pragma unroll
  for (int ff = 0; ff < 2; ++ff) {
    const int fcol = f0 + fi * 32 + ff * 16 + lr;
    const float bx_ = bin[e * TWODFF + fcol];
    const float bg_ = bin[e * TWODFF + DFF + fcol];
#pragma unroll
    for (int fm = 0; fm < 8; ++fm)
#pragma unroll
      for (int j = 0; j < 4; ++j) {
        const int row = mi * 128 + fm * 16 + orb + j;
        if (m0 + row < Me) {
          const float x = accx[fm][ff][j] + bx_;
          const float g = accg[fm][ff][j] + bg_;
          const float gl = 0.5f * g * (1.f + erff(g * 0.70710678118654752f));
          act[(size_t)tokids[row] * DFF + fcol] = f2bf(x * gl);
        }
      }
  }
}

// ---------------- GEMM2: out = p * (act @ W_out^T + b_out) ----------------
// BM=256 tok, BN=64 d-cols, BK=64, 8 waves 4m x 2d
__global__ __launch_bounds__(512) void gemm2_k(
    const short* __restrict__ act, const float* __restrict__ Wout,
    const float* __restrict__ bout, const int* __restrict__ cnt,
    const int* __restrict__ tokl, const float* __restrict__ scale,
    float* __restrict__ out) {
  const int bid = blockIdx.x + 16 * (blockIdx.y + 2 * blockIdx.z);
  const int e = bid & 7;
  const int rem = bid >> 3;
  const int n0 = (rem & 15) * 64;
  const int m0 = (rem >> 4) * 256;
  const int Me = cnt[e];
  if (m0 >= Me) return;

  __shared__ short Al[2][256 * 64];  // row stride 64 bf16 = 128 B
  __shared__ short Bl[2][64 * 64];
  __shared__ int tokids[256];
  __shared__ float pv[256];

  const int tid = threadIdx.x;
  if (tid < 256) {
    const int r = m0 + tid;
    const int tk = (r < Me) ? tokl[e * NTOK + r] : -1;
    tokids[tid] = tk;
    pv[tid] = (tk >= 0) ? scale[tk] : 0.f;
  }
  __syncthreads();

  // A staging: load i -> row = i*64 + (tid>>3), byte-col = (tid&7)*16
  const int ar0 = tid >> 3;
  const short* aP[4];
#pragma unroll
  for (int i = 0; i < 4; ++i) {
    const int row = i * 64 + ar0;
    const int tk = tokids[row];
    aP[i] = (tk >= 0) ? (act + (size_t)tk * DFF + (tid & 7) * 8) : nullptr;
  }
  // B staging: load i -> row = i*32 + (tid>>4), col = (tid&15)*4 floats
  const int br0 = tid >> 4;
  const float* bP[2];
#pragma unroll
  for (int i = 0; i < 2; ++i) {
    const int row = i * 32 + br0;
    bP[i] = Wout + (size_t)e * DDIM * DFF + (size_t)(n0 + row) * DFF + (tid & 15) * 4;
  }

  bf16x8 aR[4];
  float4 bR[2];
  auto load_t = [&](int k0) {
#pragma unroll
    for (int i = 0; i < 2; ++i) bR[i] = *(const float4*)(bP[i] + k0);
    const bf16x8 z = {0, 0, 0, 0, 0, 0, 0, 0};
#pragma unroll
    for (int i = 0; i < 4; ++i) aR[i] = aP[i] ? *(const bf16x8*)(aP[i] + k0) : z;
  };
  auto store_t = [&](int buf) {
#pragma unroll
    for (int i = 0; i < 4; ++i) {
      const int row = i * 64 + ar0;
      const int ba = (row * 128 + (tid & 7) * 16) ^ ((row & 7) << 4);
      *(bf16x8*)((char*)Al[buf] + ba) = aR[i];
    }
#pragma unroll
    for (int i = 0; i < 2; ++i) {
      const int row = i * 32 + br0;
      const int bb = (row * 128 + (tid & 15) * 8) ^ ((row & 7) << 4);
      uint2 vb;
      vb.x = pk2(bR[i].x, bR[i].y); vb.y = pk2(bR[i].z, bR[i].w);
      *(uint2*)((char*)Bl[buf] + bb) = vb;
    }
  };

  const int wid = tid >> 6, lane = tid & 63;
  const int mi = wid >> 1;            // 0..3 -> 64-row m-group
  const int di = wid & 1;             // 0..1 -> 32 d-cols
  const int lr = lane & 15;
  const int lkb = (lane >> 4) * 16;

  f32x4 acc[4][2];
  const f32x4 zf = {0.f, 0.f, 0.f, 0.f};
#pragma unroll
  for (int a = 0; a < 4; ++a) { acc[a][0] = zf; acc[a][1] = zf; }

  load_t(0);
  store_t(0);

  // DFF/BK = 4096/64 = 64 K-tiles  (round-3 bug: this was 16)
  for (int kt = 0; kt < 64; ++kt) {
    if (kt < 63) load_t((kt + 1) * 64);
    __syncthreads();
    const char* Ab = (const char*)Al[kt & 1];
    const char* Bb = (const char*)Bl[kt & 1];
#pragma unroll
    for (int ks = 0; ks < 2; ++ks) {
      bf16x8 a[4], b[2];
      const int kb = ks * 64 + lkb;
#pragma unroll
      for (int fm = 0; fm < 4; ++fm) {
        const int row = mi * 64 + fm * 16 + lr;
        a[fm] = *(const bf16x8*)(Ab + ((row * 128 + kb) ^ ((row & 7) << 4)));
      }
#pragma unroll
      for (int ff = 0; ff < 2; ++ff) {
        const int rn = di * 32 + ff * 16 + lr;
        b[ff] = *(const bf16x8*)(Bb + ((rn * 128 + kb) ^ ((rn & 7) << 4)));
      }
#pragma unroll
      for (int fm = 0; fm < 4; ++fm)
#pragma unroll
        for (int ff = 0; ff < 2; ++ff)
          acc[fm][ff] = __builtin_amdgcn_mfma_f32_16x16x32_bf16(a[fm], b[ff], acc[fm][ff], 0, 0, 0);
    }
    if (kt < 63) store_t((kt + 1) & 1);
  }

  const int orb = (lane >> 4) * 4;
#pragma unroll
  for (int ff = 0; ff < 2; ++ff) {
    const int ncol = n0 + di * 32 + ff * 16 + lr;
    const float bo = bout[e * DDIM + ncol];
#pragma unroll
    for (int fm = 0; fm < 4; ++fm)
#pragma unroll
      for (int j = 0; j < 4; ++j) {
        const int row = mi * 64 + fm * 16 + orb + j;
        if (m0 + row < Me)
          out[(size_t)tokids[row] * DDIM + ncol] = pv[row] * (acc[fm][ff][j] + bo);
      }
  }
}

extern "C" void kernel_launch(void* const* d_in, const int* in_sizes, int n_in,
                              void* d_out, int out_size, void* d_ws, size_t ws_size,
                              hipStream_t stream) {
  const float* hid = (const float*)d_in[0];
  const float* disp = (const float*)d_in[1];
  const float* comb = (const float*)d_in[2];
  const float* Win = (const float*)d_in[3];
  const float* bin = (const float*)d_in[4];
  const float* Wout = (const float*)d_in[5];
  const float* bout = (const float*)d_in[6];
  float* out = (float*)d_out;

  char* ws = (char*)d_ws;
  int* cnt = (int*)(ws);
  int* tokl = (int*)(ws + 256);
  float* scale = (float*)(ws + 256 + NTOK * NEXP * 4);
  short* act = (short*)(ws + (1 << 17));

  route_k<<<1, 256, 0, stream>>>(disp, comb, cnt, tokl, scale);
  gemm1_k<<<dim3(32, 2, NEXP), 512, 0, stream>>>(hid, Win, bin, cnt, tokl, act);
  gemm2_k<<<dim3(16, 2, NEXP), 512, 0, stream>>>(act, Wout, bout, cnt, tokl, scale, out);
}